// Round 7
// baseline (265.735 us; speedup 1.0000x reference)
//
#include <hip/hip_runtime.h>
#include <math.h>

// ---------------------------------------------------------------------------
// Qwen3.5 TopK Router, MI355X (gfx950).
// R16: convoy decorrelation done right. R15 (118us) had 16 waves/CU in only
// TWO 8-wave barrier domains -> synchronized stalls, MfmaUtil stuck ~22%.
// R16 splits blocks over EXPERTS (not tokens, R14's mistake): block =
// 32 tokens x 64 experts, 4 waves, LDS 40KB -> FOUR independent blocks/CU,
// grid 1024 = exactly one resident generation. All R15 per-wave ratios
// preserved: 5 B-loads / 30 mfma per chunk, 60-mfma body runs, same total
// B traffic. Softmax moves to a third tiny kernel (gemm writes final fp64
// logits, bit-identical combine), epilogue lifted from verified R10/R11.
//
// Numerics (unchanged, harness-verified R11-R15):
//   x = sum_i a_i 2^-(4+7i)   (5 int8 slices, |x|<8)
//   w = sum_j c_j 2^-(9+7j)   (5 int8 slices, |w|<0.25)
//   products i+j<=4 -> exact i32 diagonal accumulators, combined in fp64:
//   logit = sum_s acc_s * 2^-(13+7s).  Error ~1e-9.
//
// Fragment layouts (16x16x64 i8, verified R13/R15 passing):
//   A: lane l -> row l&15,  k = (l>>4)*16 + byte
//   B: lane l -> col l&15,  k = (l>>4)*16 + byte
//   C/D: col = l&15, row = (l>>4)*4 + reg
// ---------------------------------------------------------------------------

constexpr int T = 16384;
constexpr int D = 2048;
constexpr int E = 128;
constexpr int K = 8;

constexpr int BM  = 32;        // tokens per block
constexpr int NS  = 5;         // int8 slices per fp32
constexpr int NB2 = D / 128;   // 16 bodies of K=128 (2 chunks of 64)

typedef int i32x4 __attribute__((ext_vector_type(4)));

#define MFI8(A, B, C) C = __builtin_amdgcn_mfma_i32_16x16x64_i8(A, B, C, 0, 0, 0)

// Exact base-128 digit extraction: x ~= sum_s out[s] / (c * 128^s).
__device__ __forceinline__ void slice5(float x, float c, float ic, int out[NS]) {
    float r = x;
#pragma unroll
    for (int s = 0; s < NS; ++s) {
        float q = rintf(r * c);
        out[s] = (int)q;
        r = fmaf(q, -ic, r);
        c *= 128.f;
        ic *= (1.f / 128.f);
    }
}

// W(E,D) fp32 -> Ws[s][e][k] int8;  w = sum_j Ws[j][e][k] * 2^-(9+7j)
__global__ __launch_bounds__(256)
void w_slice(const float* __restrict__ W, signed char* __restrict__ Ws)
{
    const int e  = blockIdx.x >> 1;
    const int k0 = ((blockIdx.x & 1) << 10) | (threadIdx.x << 2);
    float4 v = *(const float4*)(W + (size_t)e * D + k0);
    int b0[NS], b1[NS], b2[NS], b3[NS];
    slice5(v.x, 512.f, 1.f / 512.f, b0);
    slice5(v.y, 512.f, 1.f / 512.f, b1);
    slice5(v.z, 512.f, 1.f / 512.f, b2);
    slice5(v.w, 512.f, 1.f / 512.f, b3);
#pragma unroll
    for (int s = 0; s < NS; ++s) {
        unsigned lo = __builtin_amdgcn_perm((unsigned)b1[s], (unsigned)b0[s], 0x00000400u);
        unsigned hi = __builtin_amdgcn_perm((unsigned)b3[s], (unsigned)b2[s], 0x00000400u);
        unsigned pk = __builtin_amdgcn_perm(hi, lo, 0x05040100u);
        *(int*)(Ws + (size_t)s * E * D + (size_t)e * D + k0) = (int)pk;
    }
}

// One block = 32 tokens x 64 experts (one half), full K. 4 waves; wave w
// owns experts [ehalf + 16w, +16) as two 16-token tiles. Final fp64 logits
// go straight to ws[t][e].
__global__ __launch_bounds__(256, 4)
void router_gemm(const float* __restrict__ X,
                 const signed char* __restrict__ Ws,
                 double* __restrict__ wsd)
{
    // A staging, double-buffered, K=128 per buffer:
    // [buf][chunk][slice][tile][kgroup][slot16][16B]   40 KB
    // slot = (token16 + 4*kgroup) & 15
    __shared__ __align__(16) signed char As[2][2][NS][2][4][16][16];

    const int tid = threadIdx.x;
    const int bx  = blockIdx.x;
    const long t0 = (long)(bx >> 1) * BM;
    const int eh  = (bx & 1) << 6;      // expert-half base: 0 or 64

    // staging roles: thread -> token ar (0..31), k-lane ak (0..7);
    // 4 float4 per body at k = 4*ak + 32*c, c = 0..3.
    const int ar = tid >> 3;
    const int ak = tid & 7;
    const float* Xp = X + (t0 + ar) * (long)D + (ak << 2);

    // mfma roles
    const int l  = tid & 63;
    const int wv = tid >> 6;    // wave 0..3 -> experts [eh+16wv, eh+16wv+16)
    const int er = l & 15;
    const int kg = l >> 4;

    const size_t wbase = (size_t)(eh + wv * 16 + er) * D + (size_t)kg * 16;
    const signed char* Wq0 = Ws + 0UL * E * D + wbase;
    const signed char* Wq1 = Ws + 1UL * E * D + wbase;
    const signed char* Wq2 = Ws + 2UL * E * D + wbase;
    const signed char* Wq3 = Ws + 3UL * E * D + wbase;
    const signed char* Wq4 = Ws + 4UL * E * D + wbase;

    // A-fragment lane offset, including the slot swizzle
    const int loff = kg * 256 + (((er + (kg << 2)) & 15) << 4);

    i32x4 e0 = {}, e1 = {}, e2 = {}, e3 = {}, e4 = {};  // tile 0 diagonals
    i32x4 f0 = {}, f1 = {}, f2 = {}, f3 = {}, f4 = {};  // tile 1 diagonals

    // convert one float4 (sub-chunk c of this thread) into As[buf]
    auto stage = [&](const float4& v, int buf, int c) {
        int q0[NS], q1[NS], q2[NS], q3[NS];
        slice5(v.x, 16.f, 1.f / 16.f, q0);
        slice5(v.y, 16.f, 1.f / 16.f, q1);
        slice5(v.z, 16.f, 1.f / 16.f, q2);
        slice5(v.w, 16.f, 1.f / 16.f, q3);
        const int chn  = c >> 1;
        const int kgv  = (ak >> 2) + ((c & 1) << 1);
        const int slot = ((ar & 15) + (kgv << 2)) & 15;
        int* dst = (int*)&As[buf][chn][0][ar >> 4][kgv][slot][(ak & 3) << 2];
#pragma unroll
        for (int s = 0; s < NS; ++s) {
            unsigned lo = __builtin_amdgcn_perm((unsigned)q1[s], (unsigned)q0[s], 0x00000400u);
            unsigned hi = __builtin_amdgcn_perm((unsigned)q3[s], (unsigned)q2[s], 0x00000400u);
            unsigned pk = __builtin_amdgcn_perm(hi, lo, 0x05040100u);
            dst[s * 512] = (int)pk;   // slice stride = 2048 B
        }
    };

    // 30 mfma for one K=64 chunk: a-index-major, both tiles interleaved.
    auto chunkMM = [&](const signed char* ap,
                       const i32x4& b0, const i32x4& b1, const i32x4& b2,
                       const i32x4& b3, const i32x4& b4) {
        i32x4 at0, at1;
        at0 = *(const i32x4*)(ap);           at1 = *(const i32x4*)(ap + 1024);
        MFI8(at0, b0, e0); MFI8(at0, b1, e1); MFI8(at0, b2, e2); MFI8(at0, b3, e3); MFI8(at0, b4, e4);
        MFI8(at1, b0, f0); MFI8(at1, b1, f1); MFI8(at1, b2, f2); MFI8(at1, b3, f3); MFI8(at1, b4, f4);
        at0 = *(const i32x4*)(ap + 2048);    at1 = *(const i32x4*)(ap + 3072);
        MFI8(at0, b0, e1); MFI8(at0, b1, e2); MFI8(at0, b2, e3); MFI8(at0, b3, e4);
        MFI8(at1, b0, f1); MFI8(at1, b1, f2); MFI8(at1, b2, f3); MFI8(at1, b3, f4);
        at0 = *(const i32x4*)(ap + 4096);    at1 = *(const i32x4*)(ap + 5120);
        MFI8(at0, b0, e2); MFI8(at0, b1, e3); MFI8(at0, b2, e4);
        MFI8(at1, b0, f2); MFI8(at1, b1, f3); MFI8(at1, b2, f4);
        at0 = *(const i32x4*)(ap + 6144);    at1 = *(const i32x4*)(ap + 7168);
        MFI8(at0, b0, e3); MFI8(at0, b1, e4);
        MFI8(at1, b0, f3); MFI8(at1, b1, f4);
        at0 = *(const i32x4*)(ap + 8192);    at1 = *(const i32x4*)(ap + 9216);
        MFI8(at0, b0, e4);
        MFI8(at1, b0, f4);
    };

    // ---- prologue: stage body 0 into buf 0; prefetch X for body 1 ----
    float4 xv0 = *(const float4*)(Xp);
    float4 xv1 = *(const float4*)(Xp + 32);
    float4 xv2 = *(const float4*)(Xp + 64);
    float4 xv3 = *(const float4*)(Xp + 96);
    stage(xv0, 0, 0); stage(xv1, 0, 1); stage(xv2, 0, 2); stage(xv3, 0, 3);
    xv0 = *(const float4*)(Xp + 128);
    xv1 = *(const float4*)(Xp + 160);
    xv2 = *(const float4*)(Xp + 192);
    xv3 = *(const float4*)(Xp + 224);
    __syncthreads();

    // ---- main loop: 16 bodies x {10 B-loads, 4 stages, 60 mfma, 1 barrier}
    for (int p = 0; p < NB2; ++p) {
        const int cur = p & 1;
        const long kb = (long)p * 128;

        // chunk-0 B fragments (L2-resident); latency hides under stage VALU
        i32x4 b00 = *(const i32x4*)(Wq0 + kb);
        i32x4 b01 = *(const i32x4*)(Wq1 + kb);
        i32x4 b02 = *(const i32x4*)(Wq2 + kb);
        i32x4 b03 = *(const i32x4*)(Wq3 + kb);
        i32x4 b04 = *(const i32x4*)(Wq4 + kb);

        if (p < NB2 - 1) {                    // stage body p+1
            stage(xv0, cur ^ 1, 0);
            stage(xv1, cur ^ 1, 1);
            stage(xv2, cur ^ 1, 2);
            stage(xv3, cur ^ 1, 3);
        }

        // chunk-1 B fragments; latency hides under chunkMM(0)'s mfma run
        i32x4 b10 = *(const i32x4*)(Wq0 + kb + 64);
        i32x4 b11 = *(const i32x4*)(Wq1 + kb + 64);
        i32x4 b12 = *(const i32x4*)(Wq2 + kb + 64);
        i32x4 b13 = *(const i32x4*)(Wq3 + kb + 64);
        i32x4 b14 = *(const i32x4*)(Wq4 + kb + 64);

        const signed char* ap =
            (const signed char*)&As[cur][0][0][0][0][0][0] + loff;
        chunkMM(ap, b00, b01, b02, b03, b04);

        if (p < NB2 - 2) {                    // prefetch X for body p+2
            const long kn = (long)(p + 2) * 128;
            xv0 = *(const float4*)(Xp + kn);
            xv1 = *(const float4*)(Xp + kn + 32);
            xv2 = *(const float4*)(Xp + kn + 64);
            xv3 = *(const float4*)(Xp + kn + 96);
        }

        chunkMM(ap + 10240, b10, b11, b12, b13, b14);

        __syncthreads();
    }

    // combine diagonals in fp64 -> final logits in ws[t][e].
    // C/D map: col(expert) = l&15, row(token-in-tile) = (l>>4)*4 + reg
#pragma unroll
    for (int r = 0; r < 4; ++r) {
        const int row = kg * 4 + r;
        const int col = eh + wv * 16 + er;
        wsd[(t0 + row) * E + col]      = (double)e0[r] * 0x1p-13 + (double)e1[r] * 0x1p-20
                                       + (double)e2[r] * 0x1p-27 + (double)e3[r] * 0x1p-34
                                       + (double)e4[r] * 0x1p-41;
        wsd[(t0 + row + 16) * E + col] = (double)f0[r] * 0x1p-13 + (double)f1[r] * 0x1p-20
                                       + (double)f2[r] * 0x1p-27 + (double)f3[r] * 0x1p-34
                                       + (double)f4[r] * 0x1p-41;
    }
}

// softmax + top-8 from fp64 logits. 16 tokens/block (16 lanes per token).
// Verified R10/R11 epilogue logic, global-sourced.
__global__ __launch_bounds__(256)
void router_top(const double* __restrict__ wsd, float* __restrict__ out)
{
    const int tid = threadIdx.x;
    const int tx  = tid & 15;
    const int tt  = tid >> 4;
    const long t  = (long)blockIdx.x * 16 + tt;

    float* outL  = out;
    float* outWt = out + (long)T * E;
    float* outId = outWt + (long)T * K;

    double acc[8];
    {
        const double* s = wsd + t * E + (tx << 3);
#pragma unroll
        for (int h = 0; h < 4; ++h) {
            double2 u = *(const double2*)(s + 2 * h);
            acc[2 * h + 0] = u.x;
            acc[2 * h + 1] = u.y;
        }
    }

    double m = acc[0];
#pragma unroll
    for (int j = 1; j < 8; ++j) m = fmax(m, acc[j]);
#pragma unroll
    for (int mask = 1; mask <= 8; mask <<= 1)
        m = fmax(m, __shfl_xor(m, mask, 64));

    float e[8]; float s = 0.f;
#pragma unroll
    for (int j = 0; j < 8; ++j) { e[j] = __expf((float)(acc[j] - m)); s += e[j]; }
#pragma unroll
    for (int mask = 1; mask <= 8; mask <<= 1)
        s += __shfl_xor(s, mask, 64);
    const float inv = 1.f / s;

    float4 st0 = {e[0] * inv, e[1] * inv, e[2] * inv, e[3] * inv};
    float4 st1 = {e[4] * inv, e[5] * inv, e[6] * inv, e[7] * inv};
    *(float4*)&outL[t * E + (tx << 3)]     = st0;
    *(float4*)&outL[t * E + (tx << 3) + 4] = st1;

    // top-8 on fp64 logits (value desc, index asc) == jax.lax.top_k order
    double v[8];
#pragma unroll
    for (int j = 0; j < 8; ++j) v[j] = acc[j];

    float pk[K]; int ik[K]; float tsum = 0.f;
#pragma unroll
    for (int r = 0; r < K; ++r) {
        double bv = -1.0e300; int bi = 0x7fffffff;
#pragma unroll
        for (int j = 0; j < 8; ++j) {
            const int idx = (tx << 3) + j;
            const bool better = (v[j] > bv) || (v[j] == bv && idx < bi);
            bv = better ? v[j] : bv;
            bi = better ? idx : bi;
        }
#pragma unroll
        for (int mask = 1; mask <= 8; mask <<= 1) {
            const double ov = __shfl_xor(bv, mask, 64);
            const int    oi = __shfl_xor(bi, mask, 64);
            const bool better = (ov > bv) || (ov == bv && oi < bi);
            bv = better ? ov : bv;
            bi = better ? oi : bi;
        }
        const float pw = __expf((float)(bv - m)) * inv;
        pk[r] = pw; ik[r] = bi; tsum += pw;
        // static-index knockout (dynamic v[bi&7] would force scratch)
        const bool own  = ((bi >> 3) == tx);
        const int  slot = bi & 7;
#pragma unroll
        for (int j = 0; j < 8; ++j)
            v[j] = (own && j == slot) ? -1.0e300 : v[j];
    }

    if (tx == 0) {
        const float rinv = 1.f / tsum;
#pragma unroll
        for (int r = 0; r < K; ++r) {
            outWt[t * K + r] = pk[r] * rinv;
            outId[t * K + r] = (float)ik[r];
        }
    }
}

extern "C" void kernel_launch(void* const* d_in, const int* in_sizes, int n_in,
                              void* d_out, int out_size, void* d_ws, size_t ws_size,
                              hipStream_t stream)
{
    const float* X = (const float*)d_in[0];
    const float* W = (const float*)d_in[1];
    float* out = (float*)d_out;

    // workspace layout: [T*E fp64 logits = 16.78 MB][Ws int8 slices = 1.31 MB]
    double* wsd = (double*)d_ws;
    signed char* Ws = (signed char*)d_ws + (size_t)T * E * sizeof(double);

    w_slice<<<dim3(E * 2), dim3(256), 0, stream>>>(W, Ws);
    router_gemm<<<dim3(2 * (T / BM)), dim3(256), 0, stream>>>(X, Ws, wsd);
    router_top<<<dim3(T / 16), dim3(256), 0, stream>>>(wsd, out);
}

// Round 8
// 252.928 us; speedup vs baseline: 1.0506x; 1.0506x over previous
//
#include <hip/hip_runtime.h>
#include <math.h>

// ---------------------------------------------------------------------------
// Qwen3.5 TopK Router, MI355X (gfx950).
// R17 = R15 fused kernel (118us, best measured) with the sync micro-structure
// rebuilt per the T3/T4/T5 catalog, after R16 falsified the convoy theory
// (4 independent barrier domains -> MfmaUtil still 22%).
//  (1) Barriers no longer drain vmcnt: __syncthreads (vmcnt0+lgkmcnt0) ->
//      asm s_waitcnt lgkmcnt(0) + raw s_barrier. X-prefetch and B-loads
//      stay in flight across barriers (the documented ~20% m97-type stall).
//      LDS cross-wave visibility only needs lgkmcnt(0).
//  (2) s_setprio(1) around each 30-MFMA cluster (T5 -- pays only when waves
//      desync, which (1) enables).
//  (3) Body order: 10 B-loads at top; MFMA cluster 0; stage-VALU (writes
//      buf^1); MFMA cluster 1; X prefetch. B1 latency hides under cluster 0,
//      stage VALU sits between this wave's MFMA runs where OTHER waves'
//      prioritized MFMAs fill the pipe.
//  (4) R15's LDS slot swizzle REVERTED (it *raised* conflicts 4.1M->6.75M;
//      model was wrong) -> plain R13 layout.
//
// Numerics (unchanged, harness-verified R11-R16):
//   x = sum_i a_i 2^-(4+7i)   (5 int8 slices, |x|<8)
//   w = sum_j c_j 2^-(9+7j)   (5 int8 slices, |w|<0.25)
//   products i+j<=4 -> exact i32 diagonal accumulators, combined in fp64:
//   logit = sum_s acc_s * 2^-(13+7s).  Error ~1e-9.
//
// Fragment layouts (16x16x64 i8, verified R13-R16 passing):
//   A: lane l -> row l&15,  k = (l>>4)*16 + byte
//   B: lane l -> col l&15,  k = (l>>4)*16 + byte
//   C/D: col = l&15, row = (l>>4)*4 + reg
// ---------------------------------------------------------------------------

constexpr int T = 16384;
constexpr int D = 2048;
constexpr int E = 128;
constexpr int K = 8;

constexpr int BM  = 32;        // tokens per block
constexpr int NS  = 5;         // int8 slices per fp32
constexpr int NB2 = D / 128;   // 16 bodies of K=128 (2 chunks of 64)

typedef int i32x4 __attribute__((ext_vector_type(4)));

#define MFI8(A, B, C) C = __builtin_amdgcn_mfma_i32_16x16x64_i8(A, B, C, 0, 0, 0)

// lgkm-only barrier: LDS visibility without draining vmem queues.
#define LGKM_BARRIER() do {                                   \
    asm volatile("s_waitcnt lgkmcnt(0)" ::: "memory");        \
    __builtin_amdgcn_s_barrier();                             \
} while (0)

// Exact base-128 digit extraction: x ~= sum_s out[s] / (c * 128^s).
__device__ __forceinline__ void slice5(float x, float c, float ic, int out[NS]) {
    float r = x;
#pragma unroll
    for (int s = 0; s < NS; ++s) {
        float q = rintf(r * c);
        out[s] = (int)q;
        r = fmaf(q, -ic, r);
        c *= 128.f;
        ic *= (1.f / 128.f);
    }
}

// W(E,D) fp32 -> Ws[s][e][k] int8;  w = sum_j Ws[j][e][k] * 2^-(9+7j)
__global__ __launch_bounds__(256)
void w_slice(const float* __restrict__ W, signed char* __restrict__ Ws)
{
    const int e  = blockIdx.x >> 1;
    const int k0 = ((blockIdx.x & 1) << 10) | (threadIdx.x << 2);
    float4 v = *(const float4*)(W + (size_t)e * D + k0);
    int b0[NS], b1[NS], b2[NS], b3[NS];
    slice5(v.x, 512.f, 1.f / 512.f, b0);
    slice5(v.y, 512.f, 1.f / 512.f, b1);
    slice5(v.z, 512.f, 1.f / 512.f, b2);
    slice5(v.w, 512.f, 1.f / 512.f, b3);
#pragma unroll
    for (int s = 0; s < NS; ++s) {
        unsigned lo = __builtin_amdgcn_perm((unsigned)b1[s], (unsigned)b0[s], 0x00000400u);
        unsigned hi = __builtin_amdgcn_perm((unsigned)b3[s], (unsigned)b2[s], 0x00000400u);
        unsigned pk = __builtin_amdgcn_perm(hi, lo, 0x05040100u);
        *(int*)(Ws + (size_t)s * E * D + (size_t)e * D + k0) = (int)pk;
    }
}

// One block = 32 tokens x all 128 experts, full K. 8 waves; wave w owns
// experts [16w, 16w+16) as two 16-token tiles sharing B fragments.
__global__ __launch_bounds__(512, 4)
void router_fused(const float* __restrict__ X,
                  const signed char* __restrict__ Ws,
                  float* __restrict__ out)
{
    // A staging, double-buffered, K=128 per buffer (plain R13 layout):
    // [buf][chunk][slice][tile][kgroup][token16][16B]   40 KB
    __shared__ __align__(16) signed char As[2][2][NS][2][4][16][16];
    __shared__ double Ld[BM][E];                                   // 32 KB

    const int tid = threadIdx.x;
    const long t0 = (long)blockIdx.x * BM;

    // staging roles: thread -> token ar (0..31), k-offset ac (0,4,...,60)
    const int ar = tid >> 4;
    const int ac = (tid & 15) << 2;
    const float* Xp = X + (t0 + ar) * (long)D + ac;

    // mfma roles
    const int l  = tid & 63;
    const int wv = tid >> 6;    // wave 0..7 -> experts [16wv, 16wv+16)
    const int er = l & 15;
    const int kg = l >> 4;

    const size_t wbase = (size_t)(wv * 16 + er) * D + (size_t)kg * 16;
    const signed char* Wq0 = Ws + 0UL * E * D + wbase;
    const signed char* Wq1 = Ws + 1UL * E * D + wbase;
    const signed char* Wq2 = Ws + 2UL * E * D + wbase;
    const signed char* Wq3 = Ws + 3UL * E * D + wbase;
    const signed char* Wq4 = Ws + 4UL * E * D + wbase;

    // A-fragment lane offset: [kg][er] order -> contiguous lane*16
    const int loff = l * 16;

    i32x4 e0 = {}, e1 = {}, e2 = {}, e3 = {}, e4 = {};  // tile 0 diagonals
    i32x4 f0 = {}, f1 = {}, f2 = {}, f3 = {}, f4 = {};  // tile 1 diagonals

    // convert one float4 -> 5 packed slice-dwords into As[buf][chn]
    auto stage = [&](const float4& v, int buf, int chn) {
        int q0[NS], q1[NS], q2[NS], q3[NS];
        slice5(v.x, 16.f, 1.f / 16.f, q0);
        slice5(v.y, 16.f, 1.f / 16.f, q1);
        slice5(v.z, 16.f, 1.f / 16.f, q2);
        slice5(v.w, 16.f, 1.f / 16.f, q3);
        int* dst = (int*)&As[buf][chn][0][ar >> 4][ac >> 4][ar & 15][ac & 15];
#pragma unroll
        for (int s = 0; s < NS; ++s) {
            unsigned lo = __builtin_amdgcn_perm((unsigned)q1[s], (unsigned)q0[s], 0x00000400u);
            unsigned hi = __builtin_amdgcn_perm((unsigned)q3[s], (unsigned)q2[s], 0x00000400u);
            unsigned pk = __builtin_amdgcn_perm(hi, lo, 0x05040100u);
            dst[s * 512] = (int)pk;   // slice stride = 2048 B
        }
    };

    // 30 mfma for one K=64 chunk: a-index-major, both tiles interleaved,
    // wrapped in setprio(1) (T5).
    auto chunkMM = [&](const signed char* ap,
                       const i32x4& b0, const i32x4& b1, const i32x4& b2,
                       const i32x4& b3, const i32x4& b4) {
        i32x4 at0, at1;
        __builtin_amdgcn_s_setprio(1);
        at0 = *(const i32x4*)(ap);           at1 = *(const i32x4*)(ap + 1024);
        MFI8(at0, b0, e0); MFI8(at0, b1, e1); MFI8(at0, b2, e2); MFI8(at0, b3, e3); MFI8(at0, b4, e4);
        MFI8(at1, b0, f0); MFI8(at1, b1, f1); MFI8(at1, b2, f2); MFI8(at1, b3, f3); MFI8(at1, b4, f4);
        at0 = *(const i32x4*)(ap + 2048);    at1 = *(const i32x4*)(ap + 3072);
        MFI8(at0, b0, e1); MFI8(at0, b1, e2); MFI8(at0, b2, e3); MFI8(at0, b3, e4);
        MFI8(at1, b0, f1); MFI8(at1, b1, f2); MFI8(at1, b2, f3); MFI8(at1, b3, f4);
        at0 = *(const i32x4*)(ap + 4096);    at1 = *(const i32x4*)(ap + 5120);
        MFI8(at0, b0, e2); MFI8(at0, b1, e3); MFI8(at0, b2, e4);
        MFI8(at1, b0, f2); MFI8(at1, b1, f3); MFI8(at1, b2, f4);
        at0 = *(const i32x4*)(ap + 6144);    at1 = *(const i32x4*)(ap + 7168);
        MFI8(at0, b0, e3); MFI8(at0, b1, e4);
        MFI8(at1, b0, f3); MFI8(at1, b1, f4);
        at0 = *(const i32x4*)(ap + 8192);    at1 = *(const i32x4*)(ap + 9216);
        MFI8(at0, b0, e4);
        MFI8(at1, b0, f4);
        __builtin_amdgcn_s_setprio(0);
    };

    // ---- prologue: stage body 0 into buf 0; prefetch X for body 1 ----
    float4 xv0, xv1;
    {
        float4 x0 = *(const float4*)(Xp);
        float4 x1 = *(const float4*)(Xp + 64);
        stage(x0, 0, 0);
        stage(x1, 0, 1);
        xv0 = *(const float4*)(Xp + 128);
        xv1 = *(const float4*)(Xp + 192);
        LGKM_BARRIER();
    }

    // ---- main loop: 16 bodies; ONE lgkm-only barrier per body ----
    for (int p = 0; p < NB2; ++p) {
        const int cur = p & 1;
        const long kb = (long)p * 128;

        // all 10 B fragments at body top (L2-resident; chunk-1's latency
        // hides under chunkMM(0)'s MFMA run)
        i32x4 b00 = *(const i32x4*)(Wq0 + kb);
        i32x4 b01 = *(const i32x4*)(Wq1 + kb);
        i32x4 b02 = *(const i32x4*)(Wq2 + kb);
        i32x4 b03 = *(const i32x4*)(Wq3 + kb);
        i32x4 b04 = *(const i32x4*)(Wq4 + kb);
        i32x4 b10 = *(const i32x4*)(Wq0 + kb + 64);
        i32x4 b11 = *(const i32x4*)(Wq1 + kb + 64);
        i32x4 b12 = *(const i32x4*)(Wq2 + kb + 64);
        i32x4 b13 = *(const i32x4*)(Wq3 + kb + 64);
        i32x4 b14 = *(const i32x4*)(Wq4 + kb + 64);

        const signed char* ap =
            (const signed char*)&As[cur][0][0][0][0][0][0] + loff;

        chunkMM(ap, b00, b01, b02, b03, b04);

        if (p < NB2 - 1) {                    // stage body p+1 (writes buf^1)
            stage(xv0, cur ^ 1, 0);
            stage(xv1, cur ^ 1, 1);
        }

        chunkMM(ap + 10240, b10, b11, b12, b13, b14);

        if (p < NB2 - 2) {                    // prefetch X for body p+2
            const long kn = (long)(p + 2) * 128;
            xv0 = *(const float4*)(Xp + kn);
            xv1 = *(const float4*)(Xp + kn + 64);
        }

        // (a) my ds_reads of buf[cur] drained (results in regs),
        // (b) my ds_writes of buf[cur^1] visible; then rendezvous.
        // vmcnt deliberately NOT drained -- X/B loads span the barrier.
        LGKM_BARRIER();
    }

    // combine diagonals in fp64 -> LDS logits.
    // C/D map: col(expert) = l&15, row(token-in-tile) = (l>>4)*4 + reg
#pragma unroll
    for (int r = 0; r < 4; ++r) {
        const int row = kg * 4 + r;
        const int col = wv * 16 + er;
        Ld[row][col]      = (double)e0[r] * 0x1p-13 + (double)e1[r] * 0x1p-20
                          + (double)e2[r] * 0x1p-27 + (double)e3[r] * 0x1p-34
                          + (double)e4[r] * 0x1p-41;
        Ld[row + 16][col] = (double)f0[r] * 0x1p-13 + (double)f1[r] * 0x1p-20
                          + (double)f2[r] * 0x1p-27 + (double)f3[r] * 0x1p-34
                          + (double)f4[r] * 0x1p-41;
    }
    __syncthreads();

    // ---- epilogue: verified R11/R13 logic; 512 threads = 32 tokens x 16 ----
    float* outL  = out;
    float* outWt = out + (long)T * E;
    float* outId = outWt + (long)T * K;
    const int tx = tid & 15;
    const int tt = tid >> 4;            // token 0..31
    const long t = t0 + tt;

    double acc[8];
#pragma unroll
    for (int j = 0; j < 8; ++j) acc[j] = Ld[tt][(tx << 3) + j];

    double m = acc[0];
#pragma unroll
    for (int j = 1; j < 8; ++j) m = fmax(m, acc[j]);
#pragma unroll
    for (int mask = 1; mask <= 8; mask <<= 1)
        m = fmax(m, __shfl_xor(m, mask, 64));

    float e[8]; float s = 0.f;
#pragma unroll
    for (int j = 0; j < 8; ++j) { e[j] = __expf((float)(acc[j] - m)); s += e[j]; }
#pragma unroll
    for (int mask = 1; mask <= 8; mask <<= 1)
        s += __shfl_xor(s, mask, 64);
    const float inv = 1.f / s;

    float4 st0 = {e[0] * inv, e[1] * inv, e[2] * inv, e[3] * inv};
    float4 st1 = {e[4] * inv, e[5] * inv, e[6] * inv, e[7] * inv};
    *(float4*)&outL[t * E + (tx << 3)]     = st0;
    *(float4*)&outL[t * E + (tx << 3) + 4] = st1;

    // top-8 on fp64 logits (value desc, index asc) == jax.lax.top_k order
    double v[8];
#pragma unroll
    for (int j = 0; j < 8; ++j) v[j] = acc[j];

    float pk[K]; int ik[K]; float tsum = 0.f;
#pragma unroll
    for (int r = 0; r < K; ++r) {
        double bv = -1.0e300; int bi = 0x7fffffff;
#pragma unroll
        for (int j = 0; j < 8; ++j) {
            const int idx = (tx << 3) + j;
            const bool better = (v[j] > bv) || (v[j] == bv && idx < bi);
            bv = better ? v[j] : bv;
            bi = better ? idx : bi;
        }
#pragma unroll
        for (int mask = 1; mask <= 8; mask <<= 1) {
            const double ov = __shfl_xor(bv, mask, 64);
            const int    oi = __shfl_xor(bi, mask, 64);
            const bool better = (ov > bv) || (ov == bv && oi < bi);
            bv = better ? ov : bv;
            bi = better ? oi : bi;
        }
        const float pw = __expf((float)(bv - m)) * inv;
        pk[r] = pw; ik[r] = bi; tsum += pw;
        // static-index knockout (dynamic v[bi&7] would force scratch)
        const bool own  = ((bi >> 3) == tx);
        const int  slot = bi & 7;
#pragma unroll
        for (int j = 0; j < 8; ++j)
            v[j] = (own && j == slot) ? -1.0e300 : v[j];
    }

    if (tx == 0) {
        const float rinv = 1.f / tsum;
#pragma unroll
        for (int r = 0; r < K; ++r) {
            outWt[t * K + r] = pk[r] * rinv;
            outId[t * K + r] = (float)ik[r];
        }
    }
}

extern "C" void kernel_launch(void* const* d_in, const int* in_sizes, int n_in,
                              void* d_out, int out_size, void* d_ws, size_t ws_size,
                              hipStream_t stream)
{
    const float* X = (const float*)d_in[0];
    const float* W = (const float*)d_in[1];
    float* out = (float*)d_out;
    signed char* Ws = (signed char*)d_ws;   // needs NS*E*D = 1.31 MB (<< ws)

    w_slice<<<dim3(E * 2), dim3(256), 0, stream>>>(W, Ws);
    router_fused<<<dim3(T / BM), dim3(512), 0, stream>>>(X, Ws, out);
}